// Round 2
// baseline (135.908 us; speedup 1.0000x reference)
//
#include <hip/hip_runtime.h>

// LocallyConnected2d: B=16, C=4, H=W=128, K=7, PAD=3, fp32.
// out[b,o,h,w] = mask[b,o,h,w] * sum_{i,t} xpad[b,i,h+dy,w+dx] * wn[o,i,h,w,t]
// cw = weight + 1 at center tap (t=24) for ALL (o,i)  [ref: .at[...,24].set(1)]
// wn = |cw| / sum_t |cw|   (L1-norm over the 49 taps)
//
// Strategy:
//  - prep kernel: xTp[i][hp][wp][b] zero-padded transpose of x (4.6 MB in ws)
//    -> main-kernel x loads are contiguous 256B/wave (b fastest in lane).
//  - main kernel: 1024 blocks x 256 thr; block = (h, 16 w-positions) x 16 b.
//    Per i-channel: stage 4ox16posx49 raw weights into LDS (coalesced; each
//    weight element fetched from HBM exactly once chip-wide), compute L1 sums
//    (+ center-delta adjust), normalize in place, then FMA loop reading LDS
//    via bank-disjoint float4s and xTp via immediate-offset scalar loads.
//    acc[4] per thread (one b, all o) -> each x value reused 4x in registers.

#define HW   128
#define PW   134          // 128 + 2*3 padding
#define NB   16
#define NC   4
#define KK   49

// ---------------- prep: padded transpose x[b][i][h][w] -> xTp[i][hp][wp][b]
__global__ __launch_bounds__(256) void lc2d_prep(const float* __restrict__ x,
                                                 float* __restrict__ xTp) {
  int idx = blockIdx.x * 256 + threadIdx.x;          // (i, hp, wp)
  if (idx >= NC * PW * PW) return;
  int wp = idx % PW;
  int r  = idx / PW;
  int hp = r % PW;
  int i  = r / PW;
  int h = hp - 3, w = wp - 3;
  bool in = (h >= 0) & (h < HW) & (w >= 0) & (w < HW);
  float v[NB];
#pragma unroll
  for (int b = 0; b < NB; ++b)
    v[b] = in ? x[((b * NC + i) * HW + h) * HW + w] : 0.0f;
  float4* dst = (float4*)(xTp + (size_t)idx * NB);
  dst[0] = make_float4(v[0],  v[1],  v[2],  v[3]);
  dst[1] = make_float4(v[4],  v[5],  v[6],  v[7]);
  dst[2] = make_float4(v[8],  v[9],  v[10], v[11]);
  dst[3] = make_float4(v[12], v[13], v[14], v[15]);
}

// ---------------- main (MODE 0: x via xTp transpose; MODE 1: direct x)
template <int MODE>
__global__ __launch_bounds__(256) void lc2d_main(const float* __restrict__ weight,
                                                 const float* __restrict__ xsrc,
                                                 float* __restrict__ out) {
  const int tid = threadIdx.x;
  const int b   = tid & 15;           // lane-fastest -> coalesced x loads
  const int pos = tid >> 4;           // 0..15 (w within block)
  const int wc  = blockIdx.x & 7;
  const int h   = blockIdx.x >> 3;    // 0..127
  const int w0  = wc * 16;
  const int w   = w0 + pos;

  // [o][pos][dy*8+dx]: pos-stride 60 floats (240B) keeps float4 reads
  // 16B-aligned and bank-disjoint across the 4 pos values in a wave.
  __shared__ __align__(16) float Wl[NC][16][60];
  __shared__ float Inv[NC][16];

  float acc[NC] = {0.f, 0.f, 0.f, 0.f};

  for (int i = 0; i < NC; ++i) {
    __syncthreads();                  // protect previous iteration's reads
    // ---- stage 4*16*49 = 3136 raw weights, fully coalesced ----
    // flat(o,i,h,w0+ps,ts) = ((o*4+i)*16384 + h*128 + w0)*49 + ps*49 + ts
    const int base = (i * 16384 + h * HW + w0) * KK;
#pragma unroll
    for (int k = 0; k < 13; ++k) {
      int f = tid + k * 256;
      if (f < 3136) {
        int o  = f / 784;
        int r  = f - o * 784;
        int ps = r / 49;
        int ts = r - ps * 49;
        int dy = ts / 7;
        int dx = ts - dy * 7;
        Wl[o][ps][dy * 8 + dx] = weight[base + o * 3211264 + r];
      }
    }
    __syncthreads();
    // ---- L1 sums per (o,pos); +1 delta at center tap t=24 (slot 27) ----
    if (tid < 64) {
      int o = tid >> 4, ps = tid & 15;
      float s = 0.f;
#pragma unroll
      for (int dy = 0; dy < 7; ++dy) {
        float4 qa = *(const float4*)&Wl[o][ps][dy * 8];
        float4 qb = *(const float4*)&Wl[o][ps][dy * 8 + 4];
        s += fabsf(qa.x) + fabsf(qa.y) + fabsf(qa.z) + fabsf(qa.w)
           + fabsf(qb.x) + fabsf(qb.y) + fabsf(qb.z);   // qb.w = pad, unused
      }
      float v = Wl[o][ps][27];          // t=24 -> dy=3,dx=3 -> slot 27
      s += fabsf(v + 1.f) - fabsf(v);   // delta applies to ALL (o,i)
      Inv[o][ps] = 1.f / s;
    }
    __syncthreads();
    // ---- normalize in place: Wl <- |cw| * inv ----
#pragma unroll
    for (int k = 0; k < 13; ++k) {
      int f = tid + k * 256;
      if (f < 3136) {
        int o  = f / 784;
        int r  = f - o * 784;
        int ps = r / 49;
        int ts = r - ps * 49;
        int dy = ts / 7;
        int dx = ts - dy * 7;
        float v = Wl[o][ps][dy * 8 + dx];
        if (ts == 24) v += 1.f;         // delta for ALL (o,i)
        Wl[o][ps][dy * 8 + dx] = fabsf(v) * Inv[o][ps];
      }
    }
    __syncthreads();
    // ---- accumulate: per dy row, 7 x values reused across 4 o's ----
    float xv[7];
#pragma unroll
    for (int dy = 0; dy < 7; ++dy) {
      if (MODE == 0) {
        const float* xr = xsrc + ((size_t)((i * PW + h + dy) * PW + w) * NB + b);
#pragma unroll
        for (int dx = 0; dx < 7; ++dx) xv[dx] = xr[dx * NB];  // imm offsets
      } else {
        int hh = h + dy - 3;
        bool hin = (hh >= 0) & (hh < HW);
#pragma unroll
        for (int dx = 0; dx < 7; ++dx) {
          int ww = w + dx - 3;
          bool in = hin & (ww >= 0) & (ww < HW);
          xv[dx] = in ? xsrc[((b * NC + i) * HW + hh) * HW + ww] : 0.f;
        }
      }
#pragma unroll
      for (int o = 0; o < NC; ++o) {
        float4 qa = *(const float4*)&Wl[o][pos][dy * 8];
        float4 qb = *(const float4*)&Wl[o][pos][dy * 8 + 4];
        acc[o] = fmaf(xv[0], qa.x, acc[o]);
        acc[o] = fmaf(xv[1], qa.y, acc[o]);
        acc[o] = fmaf(xv[2], qa.z, acc[o]);
        acc[o] = fmaf(xv[3], qa.w, acc[o]);
        acc[o] = fmaf(xv[4], qb.x, acc[o]);
        acc[o] = fmaf(xv[5], qb.y, acc[o]);
        acc[o] = fmaf(xv[6], qb.z, acc[o]);
      }
    }
  }
  // ---- fmri mask (x[b,o,h,w] != 0) + store ----
#pragma unroll
  for (int o = 0; o < NC; ++o) {
    float xc;
    if (MODE == 0)
      xc = xsrc[(size_t)((o * PW + (h + 3)) * PW + (w + 3)) * NB + b];
    else
      xc = xsrc[((b * NC + o) * HW + h) * HW + w];
    out[((b * NC + o) * HW + h) * HW + w] = (xc != 0.f) ? acc[o] : 0.f;
  }
}

extern "C" void kernel_launch(void* const* d_in, const int* in_sizes, int n_in,
                              void* d_out, int out_size, void* d_ws, size_t ws_size,
                              hipStream_t stream) {
  const float* x      = (const float*)d_in[0];   // (16,4,128,128) fp32
  const float* weight = (const float*)d_in[1];   // (1,4,4,128,128,49) fp32
  float* out = (float*)d_out;                    // (16,4,128,128) fp32

  const size_t xtp_bytes = (size_t)NC * PW * PW * NB * sizeof(float); // 4.6 MB
  if (ws_size >= xtp_bytes) {
    float* xTp = (float*)d_ws;
    lc2d_prep<<<(NC * PW * PW + 255) / 256, 256, 0, stream>>>(x, xTp);
    lc2d_main<0><<<1024, 256, 0, stream>>>(weight, xTp, out);
  } else {
    lc2d_main<1><<<1024, 256, 0, stream>>>(weight, x, out);
  }
}